// Round 5
// baseline (526.224 us; speedup 1.0000x reference)
//
#include <hip/hip_runtime.h>
#include <hip/hip_bf16.h>

typedef __bf16 bf16x8 __attribute__((ext_vector_type(8)));
typedef float f32x4 __attribute__((ext_vector_type(4)));
typedef float f32x16 __attribute__((ext_vector_type(16)));
typedef unsigned short u16;
typedef unsigned int u32;
typedef unsigned long long u64;
typedef u32 u32x4v __attribute__((ext_vector_type(4)));

#define QSCALE 0.18033688011112042f  /* log2(e)/8 : folds SCALE and exp->exp2 into Q */

__device__ __forceinline__ u16 f2b(float x) {
  __hip_bfloat16 h = __float2bfloat16(x);
  return __builtin_bit_cast(u16, h);
}

__device__ __forceinline__ float exp2_fast(float x) {
#if __has_builtin(__builtin_amdgcn_exp2f)
  return __builtin_amdgcn_exp2f(x);
#else
  float r; asm("v_exp_f32 %0, %1" : "=v"(r) : "v"(x)); return r;
#endif
}

// async global->LDS, 16B per lane; LDS dest = wave-uniform base + lane*16
__device__ __forceinline__ void gload_lds16(const void* g, void* l) {
  __builtin_amdgcn_global_load_lds((const __attribute__((address_space(1))) u32*)g,
                                   (__attribute__((address_space(3))) u32*)l, 16, 0, 0);
}

// ---------------- cast f32 -> bf16 (4 elems/thread) ----------------
__global__ __launch_bounds__(256) void cast_bf16_kernel(const float* __restrict__ src,
                                                        u16* __restrict__ dst, int n4) {
  int i = blockIdx.x * 256 + threadIdx.x;
  if (i >= n4) return;
  float4 v = ((const float4*)src)[i];
  ushort4 o;
  o.x = f2b(v.x); o.y = f2b(v.y); o.z = f2b(v.z); o.w = f2b(v.w);
  ((ushort4*)dst)[i] = o;
}

// ---------------- transpose+cast: src [R][C] f32 -> dst [C][R] bf16 ----------------
__global__ __launch_bounds__(256) void transpose_cast_kernel(const float* __restrict__ src,
                                                             u16* __restrict__ dst,
                                                             int R, int C) {
  __shared__ float t[32][33];
  int c0 = blockIdx.x * 32, r0 = blockIdx.y * 32;
  int tx = threadIdx.x, ty = threadIdx.y;
  for (int k = 0; k < 32; k += 8)
    t[ty + k][tx] = src[(size_t)(r0 + ty + k) * C + c0 + tx];
  __syncthreads();
  for (int k = 0; k < 32; k += 8)
    dst[(size_t)(c0 + ty + k) * R + r0 + tx] = f2b(t[tx][ty + k]);
}

// ---------------- mask [2048][2048] int32 -> bit-packed u64 words ----------------
__global__ __launch_bounds__(256) void maskbits_kernel(const int* __restrict__ mask,
                                                       u64* __restrict__ bits) {
  int gtid = blockIdx.x * 256 + threadIdx.x;
  int wid = gtid >> 6, lane = gtid & 63;
  int v = mask[(size_t)wid * 64 + lane];
  u64 b = __ballot(v != 0);
  if (lane == 0) bits[wid] = b;
}

// ---------------- QKV GEMM: xb[4096][1024] @ Wqkv_t[3072][1024]^T ----------------
// m97 structure: global_load_lds(16B) staging, 2 barriers per K-step.
// Epilogue scatters into Qb (pre-scaled by QSCALE) / Kb [B][H][N][64], Vt [B][H][64][N].
__global__ __launch_bounds__(256) void gemm_qkv_kernel(const u16* __restrict__ A,
                                                       const u16* __restrict__ Bt,
                                                       u16* __restrict__ Qb,
                                                       u16* __restrict__ Kb,
                                                       u16* __restrict__ Vt) {
  __shared__ u16 lA[128 * 32], lB[128 * 32];
  const int tid = threadIdx.x, lane = tid & 63, w = tid >> 6;
  const int wr = w >> 1, wc = w & 1, lrow = lane & 15, lk = lane >> 4;
  const int bm = blockIdx.y, bn = blockIdx.x;
  const int srow = tid >> 2, scol = (tid & 3) * 8;
  const u16* Arow = A + (size_t)(bm * 128 + srow) * 1024 + scol;
  const u16* Brow = Bt + (size_t)(bn * 128 + srow) * 1024 + scol;
  f32x4 acc[4][4] = {};
  for (int k0 = 0; k0 < 1024; k0 += 32) {
    __syncthreads();  // prior iteration's ds_reads done before overwrite
    gload_lds16(Arow + k0,             (char*)lA + w * 1024);
    gload_lds16(Arow + 64 * 1024 + k0, (char*)lA + 4096 + w * 1024);
    gload_lds16(Brow + k0,             (char*)lB + w * 1024);
    gload_lds16(Brow + 64 * 1024 + k0, (char*)lB + 4096 + w * 1024);
    __syncthreads();  // drains vmcnt: staged data visible
    bf16x8 af[4], bfr[4];
    for (int mi = 0; mi < 4; mi++)
      af[mi] = *(const bf16x8*)&lA[(wr * 64 + mi * 16 + lrow) * 32 + lk * 8];
    for (int ni = 0; ni < 4; ni++)
      bfr[ni] = *(const bf16x8*)&lB[(wc * 64 + ni * 16 + lrow) * 32 + lk * 8];
    for (int mi = 0; mi < 4; mi++)
      for (int ni = 0; ni < 4; ni++)
        acc[mi][ni] = __builtin_amdgcn_mfma_f32_16x16x32_bf16(af[mi], bfr[ni], acc[mi][ni], 0, 0, 0);
  }
  const int rowbase = bm * 128 + wr * 64;
  const int colbase = bn * 128 + wc * 64;
  for (int mi = 0; mi < 4; mi++)
    for (int ni = 0; ni < 4; ni++)
      for (int r = 0; r < 4; r++) {
        int row = rowbase + mi * 16 + lk * 4 + r;
        int col = colbase + ni * 16 + lrow;
        int b = row >> 11, n = row & 2047;
        int which = col >> 10, within = col & 1023;
        int h = within >> 6, d = within & 63;
        float av = acc[mi][ni][r];
        size_t bh = (size_t)(b * 16 + h);
        if (which == 0)      Qb[(bh * 2048 + n) * 64 + d] = f2b(av * QSCALE);
        else if (which == 1) Kb[(bh * 2048 + n) * 64 + d] = f2b(av);
        else                 Vt[(bh * 64 + d) * 2048 + n] = f2b(av);
      }
}

// ---------------- out-proj GEMM: attnb[4096][1024] @ Wout_t[1024][1024]^T + bias ----------------
__global__ __launch_bounds__(256) void gemm_out_kernel(const u16* __restrict__ A,
                                                       const u16* __restrict__ Bt,
                                                       const float* __restrict__ bias,
                                                       float* __restrict__ out) {
  __shared__ u16 lA[128 * 32], lB[128 * 32];
  const int tid = threadIdx.x, lane = tid & 63, w = tid >> 6;
  const int wr = w >> 1, wc = w & 1, lrow = lane & 15, lk = lane >> 4;
  const int bm = blockIdx.y, bn = blockIdx.x;
  const int srow = tid >> 2, scol = (tid & 3) * 8;
  const u16* Arow = A + (size_t)(bm * 128 + srow) * 1024 + scol;
  const u16* Brow = Bt + (size_t)(bn * 128 + srow) * 1024 + scol;
  f32x4 acc[4][4] = {};
  for (int k0 = 0; k0 < 1024; k0 += 32) {
    __syncthreads();
    gload_lds16(Arow + k0,             (char*)lA + w * 1024);
    gload_lds16(Arow + 64 * 1024 + k0, (char*)lA + 4096 + w * 1024);
    gload_lds16(Brow + k0,             (char*)lB + w * 1024);
    gload_lds16(Brow + 64 * 1024 + k0, (char*)lB + 4096 + w * 1024);
    __syncthreads();
    bf16x8 af[4], bfr[4];
    for (int mi = 0; mi < 4; mi++)
      af[mi] = *(const bf16x8*)&lA[(wr * 64 + mi * 16 + lrow) * 32 + lk * 8];
    for (int ni = 0; ni < 4; ni++)
      bfr[ni] = *(const bf16x8*)&lB[(wc * 64 + ni * 16 + lrow) * 32 + lk * 8];
    for (int mi = 0; mi < 4; mi++)
      for (int ni = 0; ni < 4; ni++)
        acc[mi][ni] = __builtin_amdgcn_mfma_f32_16x16x32_bf16(af[mi], bfr[ni], acc[mi][ni], 0, 0, 0);
  }
  const int rowbase = bm * 128 + wr * 64;
  const int colbase = bn * 128 + wc * 64;
  for (int mi = 0; mi < 4; mi++)
    for (int ni = 0; ni < 4; ni++)
      for (int r = 0; r < 4; r++) {
        int row = rowbase + mi * 16 + lk * 4 + r;
        int col = colbase + ni * 16 + lrow;
        out[(size_t)row * 1024 + col] = acc[mi][ni][r] + bias[col];
      }
}

// ---------------- flash attention: swapped QK^T (32x32 MFMA), LDS P-repack, KV-split x2 ----
// grid (16, 32), block 512 = 8 waves. Wave w: q-tile (w&3), kv half (w>>2) of 1024.
// Per-wave partials (O^T, m, l) merged through LDS at the end (exact rescale-add).
__global__ __launch_bounds__(512, 4) void attn_kernel(const u16* __restrict__ Qb,
                                                      const u16* __restrict__ Kb,
                                                      const u16* __restrict__ Vt,
                                                      const u64* __restrict__ Mb,
                                                      u16* __restrict__ attnb) {
  __shared__ u32 Plds[8][32 * 32];      // per-wave [kvpair=32][q=32]
  __shared__ float comb[2][34][64];     // two-phase partial exchange
  const int tid = threadIdx.x, lane = tid & 63, w = tid >> 6;
  const int l31 = lane & 31, hi = lane >> 5;
  const int qtile = w & 3, kvh = w >> 2;
  const int qt = blockIdx.x, bh = blockIdx.y;
  const int h = bh & 15, b = bh >> 4;
  const int q = qt * 128 + qtile * 32 + l31;
  const int kv0 = kvh * 1024, kvend = kv0 + 1024;
  const u16* Qp = Qb + (size_t)bh * 2048 * 64;
  const u16* Kp = Kb + (size_t)bh * 2048 * 64;
  const u16* Vp = Vt + (size_t)bh * 64 * 2048;
  const u64* Mrow = Mb + (size_t)q * 32;
  u32* myP = &Plds[w][0];

  // Q B-frags: col=q=lane&31, k-half by hi; resident whole kernel
  bf16x8 qf[4];
#pragma unroll
  for (int t = 0; t < 4; t++)
    qf[t] = *(const bf16x8*)&Qp[(size_t)q * 64 + t * 16 + hi * 8];

  f32x16 acc0 = {}, acc1 = {};  // O^T: d in [0,32) / [32,64), col=q
  float m_run = -3.0e38f, lsum = 0.f;

  // K A-frags (row=kv, k-half by hi), double-buffered across chunks
  bf16x8 kA[2][4], kB[2][4];
#pragma unroll
  for (int t2 = 0; t2 < 2; t2++)
#pragma unroll
    for (int t = 0; t < 4; t++)
      kA[t2][t] = *(const bf16x8*)&Kp[(size_t)(kv0 + t2 * 32 + l31) * 64 + t * 16 + hi * 8];

  auto body = [&](bf16x8 (&kc)[2][4], bf16x8 (&kn)[2][4], int j0) {
    u64 mw = Mrow[j0 >> 6];
    // V A-frags for this chunk, issued early (consumed after softmax)
    bf16x8 va[2][4];
#pragma unroll
    for (int dt = 0; dt < 2; dt++)
#pragma unroll
      for (int kk = 0; kk < 4; kk++)
        va[dt][kk] = *(const bf16x8*)&Vp[(size_t)(dt * 32 + l31) * 2048 + j0 + kk * 16 + hi * 8];

    // S^T = K·Q^T over d=64 (log2-scaled already)
    f32x16 s0 = {}, s1 = {};
    __builtin_amdgcn_s_setprio(1);
#pragma unroll
    for (int t = 0; t < 4; t++) {
      s0 = __builtin_amdgcn_mfma_f32_32x32x16_bf16(kc[0][t], qf[t], s0, 0, 0, 0);
      s1 = __builtin_amdgcn_mfma_f32_32x32x16_bf16(kc[1][t], qf[t], s1, 0, 0, 0);
    }
    __builtin_amdgcn_s_setprio(0);

    // prefetch next chunk's K frags (within this wave's kv half)
    if (j0 + 64 < kvend) {
#pragma unroll
      for (int t2 = 0; t2 < 2; t2++)
#pragma unroll
        for (int t = 0; t < 4; t++)
          kn[t2][t] = *(const bf16x8*)&Kp[(size_t)(j0 + 64 + t2 * 32 + l31) * 64 + t * 16 + hi * 8];
    }

    // raw row-max (mask applied later by zeroing p; same softmax), tree + partner
    float mx[8];
#pragma unroll
    for (int i = 0; i < 8; i++)
      mx[i] = fmaxf(fmaxf(s0[i], s0[i + 8]), fmaxf(s1[i], s1[i + 8]));
    float m01 = fmaxf(mx[0], mx[1]), m23 = fmaxf(mx[2], mx[3]);
    float m45 = fmaxf(mx[4], mx[5]), m67 = fmaxf(mx[6], mx[7]);
    float pm = fmaxf(fmaxf(m01, m23), fmaxf(m45, m67));
    pm = fmaxf(pm, __shfl_xor(pm, 32, 64));

    // deferred rescale (THR=8 in log2 domain -> p bounded by 256)
    if (__any(pm > m_run + 8.f)) {
      float mn = fmaxf(m_run, pm);
      float fs = exp2_fast(m_run - mn);
      m_run = mn;
      lsum *= fs;
      acc0 *= fs;
      acc1 *= fs;
    }

    // p = exp2(s - m), mask-zero, partial sums, pack kv-pairs -> LDS [kv/2][q]
    u32 w0s = (u32)(mw >> (4 * hi));          // tile0 bits, pre-shifted by 4*hi
    u32 w1s = (u32)((mw >> 32) >> (4 * hi));  // tile1 bits
#pragma unroll
    for (int p = 0; p < 8; p++) {
      const int r0 = 2 * p;
      const int sh = (r0 & 3) + 8 * (p >> 1);           // kv_local - 4*hi for reg r0
      const int wrow = (p & 1) + 4 * (p >> 1) + 2 * hi; // kv pair row (tile0)
      float a0 = exp2_fast(s0[r0] - m_run);
      float a1 = exp2_fast(s0[r0 + 1] - m_run);
      float b0 = exp2_fast(s1[r0] - m_run);
      float b1 = exp2_fast(s1[r0 + 1] - m_run);
      a0 = ((w0s >> sh) & 1u) ? a0 : 0.f;
      a1 = ((w0s >> (sh + 1)) & 1u) ? a1 : 0.f;
      b0 = ((w1s >> sh) & 1u) ? b0 : 0.f;
      b1 = ((w1s >> (sh + 1)) & 1u) ? b1 : 0.f;
      lsum += (a0 + a1) + (b0 + b1);
      myP[wrow * 32 + l31]        = (u32)f2b(a0) | ((u32)f2b(a1) << 16);
      myP[(wrow + 16) * 32 + l31] = (u32)f2b(b0) | ((u32)f2b(b1) << 16);
    }

    // PV: B-frags read back from LDS (contiguous kv per lane), A = V^T
    asm volatile("s_waitcnt lgkmcnt(0)" ::: "memory");
    __builtin_amdgcn_s_setprio(1);
#pragma unroll
    for (int kk = 0; kk < 4; kk++) {
      const int base = (kk * 8 + hi * 4) * 32 + l31;
      u32 r0 = myP[base];
      u32 r1 = myP[base + 32];
      u32 r2 = myP[base + 64];
      u32 r3 = myP[base + 96];
      u32x4v pv4 = {r0, r1, r2, r3};
      bf16x8 pbf = __builtin_bit_cast(bf16x8, pv4);
      acc0 = __builtin_amdgcn_mfma_f32_32x32x16_bf16(va[0][kk], pbf, acc0, 0, 0, 0);
      acc1 = __builtin_amdgcn_mfma_f32_32x32x16_bf16(va[1][kk], pbf, acc1, 0, 0, 0);
    }
    __builtin_amdgcn_s_setprio(0);
  };

  for (int j0 = kv0; j0 < kvend; j0 += 128) {
    body(kA, kB, j0);
    body(kB, kA, j0 + 64);
  }

  // ---- two-phase cross-wave combine: waves 4-7 publish, waves 0-3 merge+store ----
#pragma unroll
  for (int ph = 0; ph < 2; ph++) {
    if (kvh == 1 && (qtile >> 1) == ph) {
      float* cb = &comb[qtile & 1][0][0];
      cb[0 * 64 + lane] = m_run;
      cb[1 * 64 + lane] = lsum;
#pragma unroll
      for (int r = 0; r < 16; r++) {
        cb[(2 + r) * 64 + lane]  = acc0[r];
        cb[(18 + r) * 64 + lane] = acc1[r];
      }
    }
    __syncthreads();
    if (kvh == 0 && (qtile >> 1) == ph) {
      const float* cb = &comb[qtile & 1][0][0];
      float mB = cb[0 * 64 + lane];
      float lB_ = cb[1 * 64 + lane];
      float mT = fmaxf(m_run, mB);
      float fA = exp2_fast(m_run - mT);
      float fB = exp2_fast(mB - mT);
      float lt = lsum * fA + lB_ * fB;
      lt += __shfl_xor(lt, 32, 64);
      float inv = 1.0f / lt;
#pragma unroll
      for (int r = 0; r < 16; r++) {
        acc0[r] = acc0[r] * fA + cb[(2 + r) * 64 + lane] * fB;
        acc1[r] = acc1[r] * fA + cb[(18 + r) * 64 + lane] * fB;
      }
      u16* orow = attnb + ((size_t)b * 2048 + q) * 1024 + h * 64;
#pragma unroll
      for (int rq = 0; rq < 4; rq++) {
        const int rb = rq * 4;
        {
          u32 lo = (u32)f2b(acc0[rb] * inv) | ((u32)f2b(acc0[rb + 1] * inv) << 16);
          u32 hi2 = (u32)f2b(acc0[rb + 2] * inv) | ((u32)f2b(acc0[rb + 3] * inv) << 16);
          uint2 st; st.x = lo; st.y = hi2;
          *(uint2*)(orow + 8 * rq + 4 * hi) = st;
        }
        {
          u32 lo = (u32)f2b(acc1[rb] * inv) | ((u32)f2b(acc1[rb + 1] * inv) << 16);
          u32 hi2 = (u32)f2b(acc1[rb + 2] * inv) | ((u32)f2b(acc1[rb + 3] * inv) << 16);
          uint2 st; st.x = lo; st.y = hi2;
          *(uint2*)(orow + 32 + 8 * rq + 4 * hi) = st;
        }
      }
    }
    __syncthreads();  // protect comb before phase-1 overwrite
  }
}

extern "C" void kernel_launch(void* const* d_in, const int* in_sizes, int n_in,
                              void* d_out, int out_size, void* d_ws, size_t ws_size,
                              hipStream_t stream) {
  const float* x    = (const float*)d_in[0];
  const int*   mask = (const int*)d_in[1];
  const float* Wqkv = (const float*)d_in[2];
  const float* Wout = (const float*)d_in[3];
  const float* bout = (const float*)d_in[4];
  float* out = (float*)d_out;

  char* ws = (char*)d_ws;
  // layout (bytes): [0,8M) xb / attnb; [8M,14M) Wqkv_t, later [8M,10M) Wout_t + [10M,10.5M) maskbits;
  // [14M,22M) Qb; [22M,30M) Kb; [30M,38M) Vt
  u16* xb     = (u16*)(ws);
  u16* attnb  = xb;
  u16* Wqkv_t = (u16*)(ws + (size_t)(8u << 20));
  u16* Wout_t = Wqkv_t;
  u64* mbits  = (u64*)(ws + (size_t)(10u << 20));
  u16* Qb     = (u16*)(ws + (size_t)(14u << 20));
  u16* Kb     = (u16*)(ws + (size_t)(22u << 20));
  u16* Vt     = (u16*)(ws + (size_t)(30u << 20));

  cast_bf16_kernel<<<4096, 256, 0, stream>>>(x, xb, 4096 * 1024 / 4);
  transpose_cast_kernel<<<dim3(96, 32), dim3(32, 8), 0, stream>>>(Wqkv, Wqkv_t, 1024, 3072);
  gemm_qkv_kernel<<<dim3(24, 32), 256, 0, stream>>>(xb, Wqkv_t, Qb, Kb, Vt);
  transpose_cast_kernel<<<dim3(32, 32), dim3(32, 8), 0, stream>>>(Wout, Wout_t, 1024, 1024);
  maskbits_kernel<<<16384, 256, 0, stream>>>(mask, mbits);
  attn_kernel<<<dim3(16, 32), 512, 0, stream>>>(Qb, Kb, Vt, mbits, attnb);
  gemm_out_kernel<<<dim3(8, 32), 256, 0, stream>>>(attnb, Wout_t, bout, out);
}

// Round 6
// 218.538 us; speedup vs baseline: 2.4079x; 2.4079x over previous
//
#include <hip/hip_runtime.h>
#include <hip/hip_bf16.h>

typedef __bf16 bf16x8 __attribute__((ext_vector_type(8)));
typedef float f32x4 __attribute__((ext_vector_type(4)));
typedef float f32x16 __attribute__((ext_vector_type(16)));
typedef unsigned short u16;
typedef unsigned int u32;
typedef unsigned long long u64;
typedef u32 u32x4v __attribute__((ext_vector_type(4)));

#define QSCALE 0.18033688011112042f  /* log2(e)/8 : folds SCALE and exp->exp2 into Q */

__device__ __forceinline__ u16 f2b(float x) {
  __hip_bfloat16 h = __float2bfloat16(x);
  return __builtin_bit_cast(u16, h);
}

__device__ __forceinline__ float exp2_fast(float x) {
#if __has_builtin(__builtin_amdgcn_exp2f)
  return __builtin_amdgcn_exp2f(x);
#else
  float r; asm("v_exp_f32 %0, %1" : "=v"(r) : "v"(x)); return r;
#endif
}

// async global->LDS, 16B per lane; LDS dest = wave-uniform base + lane*16
__device__ __forceinline__ void gload_lds16(const void* g, void* l) {
  __builtin_amdgcn_global_load_lds((const __attribute__((address_space(1))) u32*)g,
                                   (__attribute__((address_space(3))) u32*)l, 16, 0, 0);
}

// ---------------- cast f32 -> bf16 (4 elems/thread) ----------------
__global__ __launch_bounds__(256) void cast_bf16_kernel(const float* __restrict__ src,
                                                        u16* __restrict__ dst, int n4) {
  int i = blockIdx.x * 256 + threadIdx.x;
  if (i >= n4) return;
  float4 v = ((const float4*)src)[i];
  ushort4 o;
  o.x = f2b(v.x); o.y = f2b(v.y); o.z = f2b(v.z); o.w = f2b(v.w);
  ((ushort4*)dst)[i] = o;
}

// ---------------- transpose+cast: src [R][C] f32 -> dst [C][R] bf16 ----------------
__global__ __launch_bounds__(256) void transpose_cast_kernel(const float* __restrict__ src,
                                                             u16* __restrict__ dst,
                                                             int R, int C) {
  __shared__ float t[32][33];
  int c0 = blockIdx.x * 32, r0 = blockIdx.y * 32;
  int tx = threadIdx.x, ty = threadIdx.y;
  for (int k = 0; k < 32; k += 8)
    t[ty + k][tx] = src[(size_t)(r0 + ty + k) * C + c0 + tx];
  __syncthreads();
  for (int k = 0; k < 32; k += 8)
    dst[(size_t)(c0 + ty + k) * R + r0 + tx] = f2b(t[tx][ty + k]);
}

// ---------------- mask [2048][2048] int32 -> bit-packed u64 words ----------------
__global__ __launch_bounds__(256) void maskbits_kernel(const int* __restrict__ mask,
                                                       u64* __restrict__ bits) {
  int gtid = blockIdx.x * 256 + threadIdx.x;
  int wid = gtid >> 6, lane = gtid & 63;
  int v = mask[(size_t)wid * 64 + lane];
  u64 b = __ballot(v != 0);
  if (lane == 0) bits[wid] = b;
}

// ---------------- QKV GEMM: xb[4096][1024] @ Wqkv_t[3072][1024]^T ----------------
// m97 structure: global_load_lds(16B) staging, 2 barriers per K-step.
// Epilogue scatters into Qb (pre-scaled by QSCALE) / Kb [B][H][N][64], Vt [B][H][64][N].
__global__ __launch_bounds__(256) void gemm_qkv_kernel(const u16* __restrict__ A,
                                                       const u16* __restrict__ Bt,
                                                       u16* __restrict__ Qb,
                                                       u16* __restrict__ Kb,
                                                       u16* __restrict__ Vt) {
  __shared__ u16 lA[128 * 32], lB[128 * 32];
  const int tid = threadIdx.x, lane = tid & 63, w = tid >> 6;
  const int wr = w >> 1, wc = w & 1, lrow = lane & 15, lk = lane >> 4;
  const int bm = blockIdx.y, bn = blockIdx.x;
  const int srow = tid >> 2, scol = (tid & 3) * 8;
  const u16* Arow = A + (size_t)(bm * 128 + srow) * 1024 + scol;
  const u16* Brow = Bt + (size_t)(bn * 128 + srow) * 1024 + scol;
  f32x4 acc[4][4] = {};
  for (int k0 = 0; k0 < 1024; k0 += 32) {
    __syncthreads();  // prior iteration's ds_reads done before overwrite
    gload_lds16(Arow + k0,             (char*)lA + w * 1024);
    gload_lds16(Arow + 64 * 1024 + k0, (char*)lA + 4096 + w * 1024);
    gload_lds16(Brow + k0,             (char*)lB + w * 1024);
    gload_lds16(Brow + 64 * 1024 + k0, (char*)lB + 4096 + w * 1024);
    __syncthreads();  // drains vmcnt: staged data visible
    bf16x8 af[4], bfr[4];
    for (int mi = 0; mi < 4; mi++)
      af[mi] = *(const bf16x8*)&lA[(wr * 64 + mi * 16 + lrow) * 32 + lk * 8];
    for (int ni = 0; ni < 4; ni++)
      bfr[ni] = *(const bf16x8*)&lB[(wc * 64 + ni * 16 + lrow) * 32 + lk * 8];
    for (int mi = 0; mi < 4; mi++)
      for (int ni = 0; ni < 4; ni++)
        acc[mi][ni] = __builtin_amdgcn_mfma_f32_16x16x32_bf16(af[mi], bfr[ni], acc[mi][ni], 0, 0, 0);
  }
  const int rowbase = bm * 128 + wr * 64;
  const int colbase = bn * 128 + wc * 64;
  for (int mi = 0; mi < 4; mi++)
    for (int ni = 0; ni < 4; ni++)
      for (int r = 0; r < 4; r++) {
        int row = rowbase + mi * 16 + lk * 4 + r;
        int col = colbase + ni * 16 + lrow;
        int b = row >> 11, n = row & 2047;
        int which = col >> 10, within = col & 1023;
        int h = within >> 6, d = within & 63;
        float av = acc[mi][ni][r];
        size_t bh = (size_t)(b * 16 + h);
        if (which == 0)      Qb[(bh * 2048 + n) * 64 + d] = f2b(av * QSCALE);
        else if (which == 1) Kb[(bh * 2048 + n) * 64 + d] = f2b(av);
        else                 Vt[(bh * 64 + d) * 2048 + n] = f2b(av);
      }
}

// ---------------- out-proj GEMM: attnb[4096][1024] @ Wout_t[1024][1024]^T + bias ----------------
__global__ __launch_bounds__(256) void gemm_out_kernel(const u16* __restrict__ A,
                                                       const u16* __restrict__ Bt,
                                                       const float* __restrict__ bias,
                                                       float* __restrict__ out) {
  __shared__ u16 lA[128 * 32], lB[128 * 32];
  const int tid = threadIdx.x, lane = tid & 63, w = tid >> 6;
  const int wr = w >> 1, wc = w & 1, lrow = lane & 15, lk = lane >> 4;
  const int bm = blockIdx.y, bn = blockIdx.x;
  const int srow = tid >> 2, scol = (tid & 3) * 8;
  const u16* Arow = A + (size_t)(bm * 128 + srow) * 1024 + scol;
  const u16* Brow = Bt + (size_t)(bn * 128 + srow) * 1024 + scol;
  f32x4 acc[4][4] = {};
  for (int k0 = 0; k0 < 1024; k0 += 32) {
    __syncthreads();
    gload_lds16(Arow + k0,             (char*)lA + w * 1024);
    gload_lds16(Arow + 64 * 1024 + k0, (char*)lA + 4096 + w * 1024);
    gload_lds16(Brow + k0,             (char*)lB + w * 1024);
    gload_lds16(Brow + 64 * 1024 + k0, (char*)lB + 4096 + w * 1024);
    __syncthreads();
    bf16x8 af[4], bfr[4];
    for (int mi = 0; mi < 4; mi++)
      af[mi] = *(const bf16x8*)&lA[(wr * 64 + mi * 16 + lrow) * 32 + lk * 8];
    for (int ni = 0; ni < 4; ni++)
      bfr[ni] = *(const bf16x8*)&lB[(wc * 64 + ni * 16 + lrow) * 32 + lk * 8];
    for (int mi = 0; mi < 4; mi++)
      for (int ni = 0; ni < 4; ni++)
        acc[mi][ni] = __builtin_amdgcn_mfma_f32_16x16x32_bf16(af[mi], bfr[ni], acc[mi][ni], 0, 0, 0);
  }
  const int rowbase = bm * 128 + wr * 64;
  const int colbase = bn * 128 + wc * 64;
  for (int mi = 0; mi < 4; mi++)
    for (int ni = 0; ni < 4; ni++)
      for (int r = 0; r < 4; r++) {
        int row = rowbase + mi * 16 + lk * 4 + r;
        int col = colbase + ni * 16 + lrow;
        out[(size_t)row * 1024 + col] = acc[mi][ni][r] + bias[col];
      }
}

// ---------------- flash attention: swapped QK^T (32x32 MFMA), LDS P-repack, KV-split x2 ----
// grid (16, 32), block 512 = 8 waves. Wave w: q-tile (w&3), kv half (w>>2) of 1024.
// __launch_bounds__(512, 2): hipcc treats arg2 as BLOCKS/CU -> 16 waves/CU -> VGPR cap 128.
// (512,4) capped VGPR at 64 and spilled ~2GB to scratch — round-5 regression.
__global__ __launch_bounds__(512, 2) void attn_kernel(const u16* __restrict__ Qb,
                                                      const u16* __restrict__ Kb,
                                                      const u16* __restrict__ Vt,
                                                      const u64* __restrict__ Mb,
                                                      u16* __restrict__ attnb) {
  __shared__ u32 Plds[8][32 * 32];      // per-wave [kvpair=32][q=32]
  __shared__ float comb[2][34][64];     // two-phase partial exchange
  const int tid = threadIdx.x, lane = tid & 63, w = tid >> 6;
  const int l31 = lane & 31, hi = lane >> 5;
  const int qtile = w & 3, kvh = w >> 2;
  const int qt = blockIdx.x, bh = blockIdx.y;
  const int h = bh & 15, b = bh >> 4;
  const int q = qt * 128 + qtile * 32 + l31;
  const int kv0 = kvh * 1024, kvend = kv0 + 1024;
  const u16* Qp = Qb + (size_t)bh * 2048 * 64;
  const u16* Kp = Kb + (size_t)bh * 2048 * 64;
  const u16* Vp = Vt + (size_t)bh * 64 * 2048;
  const u64* Mrow = Mb + (size_t)q * 32;
  u32* myP = &Plds[w][0];

  // Q B-frags: col=q=lane&31, k-half by hi; resident whole kernel
  bf16x8 qf[4];
#pragma unroll
  for (int t = 0; t < 4; t++)
    qf[t] = *(const bf16x8*)&Qp[(size_t)q * 64 + t * 16 + hi * 8];

  f32x16 acc0 = {}, acc1 = {};  // O^T: d in [0,32) / [32,64), col=q
  float m_run = -3.0e38f, lsum = 0.f;

  // K A-frags (row=kv, k-half by hi), double-buffered across chunks
  bf16x8 kA[2][4], kB[2][4];
#pragma unroll
  for (int t2 = 0; t2 < 2; t2++)
#pragma unroll
    for (int t = 0; t < 4; t++)
      kA[t2][t] = *(const bf16x8*)&Kp[(size_t)(kv0 + t2 * 32 + l31) * 64 + t * 16 + hi * 8];

  auto body = [&](bf16x8 (&kc)[2][4], bf16x8 (&kn)[2][4], int j0) {
    u64 mw = Mrow[j0 >> 6];
    // V A-frags for this chunk, issued early (consumed after softmax)
    bf16x8 va[2][4];
#pragma unroll
    for (int dt = 0; dt < 2; dt++)
#pragma unroll
      for (int kk = 0; kk < 4; kk++)
        va[dt][kk] = *(const bf16x8*)&Vp[(size_t)(dt * 32 + l31) * 2048 + j0 + kk * 16 + hi * 8];

    // S^T = K·Q^T over d=64 (log2-scaled already)
    f32x16 s0 = {}, s1 = {};
    __builtin_amdgcn_s_setprio(1);
#pragma unroll
    for (int t = 0; t < 4; t++) {
      s0 = __builtin_amdgcn_mfma_f32_32x32x16_bf16(kc[0][t], qf[t], s0, 0, 0, 0);
      s1 = __builtin_amdgcn_mfma_f32_32x32x16_bf16(kc[1][t], qf[t], s1, 0, 0, 0);
    }
    __builtin_amdgcn_s_setprio(0);

    // prefetch next chunk's K frags (within this wave's kv half)
    if (j0 + 64 < kvend) {
#pragma unroll
      for (int t2 = 0; t2 < 2; t2++)
#pragma unroll
        for (int t = 0; t < 4; t++)
          kn[t2][t] = *(const bf16x8*)&Kp[(size_t)(j0 + 64 + t2 * 32 + l31) * 64 + t * 16 + hi * 8];
    }

    // raw row-max (mask applied later by zeroing p; same softmax), tree + partner
    float mx[8];
#pragma unroll
    for (int i = 0; i < 8; i++)
      mx[i] = fmaxf(fmaxf(s0[i], s0[i + 8]), fmaxf(s1[i], s1[i + 8]));
    float m01 = fmaxf(mx[0], mx[1]), m23 = fmaxf(mx[2], mx[3]);
    float m45 = fmaxf(mx[4], mx[5]), m67 = fmaxf(mx[6], mx[7]);
    float pm = fmaxf(fmaxf(m01, m23), fmaxf(m45, m67));
    pm = fmaxf(pm, __shfl_xor(pm, 32, 64));

    // deferred rescale (THR=8 in log2 domain -> p bounded by 256)
    if (__any(pm > m_run + 8.f)) {
      float mn = fmaxf(m_run, pm);
      float fs = exp2_fast(m_run - mn);
      m_run = mn;
      lsum *= fs;
      acc0 *= fs;
      acc1 *= fs;
    }

    // p = exp2(s - m), mask-zero, partial sums, pack kv-pairs -> LDS [kv/2][q]
    u32 w0s = (u32)(mw >> (4 * hi));          // tile0 bits, pre-shifted by 4*hi
    u32 w1s = (u32)((mw >> 32) >> (4 * hi));  // tile1 bits
#pragma unroll
    for (int p = 0; p < 8; p++) {
      const int r0 = 2 * p;
      const int sh = (r0 & 3) + 8 * (p >> 1);           // kv_local - 4*hi for reg r0
      const int wrow = (p & 1) + 4 * (p >> 1) + 2 * hi; // kv pair row (tile0)
      float a0 = exp2_fast(s0[r0] - m_run);
      float a1 = exp2_fast(s0[r0 + 1] - m_run);
      float b0 = exp2_fast(s1[r0] - m_run);
      float b1 = exp2_fast(s1[r0 + 1] - m_run);
      a0 = ((w0s >> sh) & 1u) ? a0 : 0.f;
      a1 = ((w0s >> (sh + 1)) & 1u) ? a1 : 0.f;
      b0 = ((w1s >> sh) & 1u) ? b0 : 0.f;
      b1 = ((w1s >> (sh + 1)) & 1u) ? b1 : 0.f;
      lsum += (a0 + a1) + (b0 + b1);
      myP[wrow * 32 + l31]        = (u32)f2b(a0) | ((u32)f2b(a1) << 16);
      myP[(wrow + 16) * 32 + l31] = (u32)f2b(b0) | ((u32)f2b(b1) << 16);
    }

    // PV: B-frags read back from LDS (contiguous kv per lane), A = V^T
    asm volatile("s_waitcnt lgkmcnt(0)" ::: "memory");
    __builtin_amdgcn_s_setprio(1);
#pragma unroll
    for (int kk = 0; kk < 4; kk++) {
      const int base = (kk * 8 + hi * 4) * 32 + l31;
      u32 r0 = myP[base];
      u32 r1 = myP[base + 32];
      u32 r2 = myP[base + 64];
      u32 r3 = myP[base + 96];
      u32x4v pv4 = {r0, r1, r2, r3};
      bf16x8 pbf = __builtin_bit_cast(bf16x8, pv4);
      acc0 = __builtin_amdgcn_mfma_f32_32x32x16_bf16(va[0][kk], pbf, acc0, 0, 0, 0);
      acc1 = __builtin_amdgcn_mfma_f32_32x32x16_bf16(va[1][kk], pbf, acc1, 0, 0, 0);
    }
    __builtin_amdgcn_s_setprio(0);
  };

  for (int j0 = kv0; j0 < kvend; j0 += 128) {
    body(kA, kB, j0);
    body(kB, kA, j0 + 64);
  }

  // ---- two-phase cross-wave combine: waves 4-7 publish, waves 0-3 merge+store ----
#pragma unroll
  for (int ph = 0; ph < 2; ph++) {
    if (kvh == 1 && (qtile >> 1) == ph) {
      float* cb = &comb[qtile & 1][0][0];
      cb[0 * 64 + lane] = m_run;
      cb[1 * 64 + lane] = lsum;
#pragma unroll
      for (int r = 0; r < 16; r++) {
        cb[(2 + r) * 64 + lane]  = acc0[r];
        cb[(18 + r) * 64 + lane] = acc1[r];
      }
    }
    __syncthreads();
    if (kvh == 0 && (qtile >> 1) == ph) {
      const float* cb = &comb[qtile & 1][0][0];
      float mB = cb[0 * 64 + lane];
      float lB_ = cb[1 * 64 + lane];
      float mT = fmaxf(m_run, mB);
      float fA = exp2_fast(m_run - mT);
      float fB = exp2_fast(mB - mT);
      float lt = lsum * fA + lB_ * fB;
      lt += __shfl_xor(lt, 32, 64);
      float inv = 1.0f / lt;
#pragma unroll
      for (int r = 0; r < 16; r++) {
        acc0[r] = acc0[r] * fA + cb[(2 + r) * 64 + lane] * fB;
        acc1[r] = acc1[r] * fA + cb[(18 + r) * 64 + lane] * fB;
      }
      u16* orow = attnb + ((size_t)b * 2048 + q) * 1024 + h * 64;
#pragma unroll
      for (int rq = 0; rq < 4; rq++) {
        const int rb = rq * 4;
        {
          u32 lo = (u32)f2b(acc0[rb] * inv) | ((u32)f2b(acc0[rb + 1] * inv) << 16);
          u32 hi2 = (u32)f2b(acc0[rb + 2] * inv) | ((u32)f2b(acc0[rb + 3] * inv) << 16);
          uint2 st; st.x = lo; st.y = hi2;
          *(uint2*)(orow + 8 * rq + 4 * hi) = st;
        }
        {
          u32 lo = (u32)f2b(acc1[rb] * inv) | ((u32)f2b(acc1[rb + 1] * inv) << 16);
          u32 hi2 = (u32)f2b(acc1[rb + 2] * inv) | ((u32)f2b(acc1[rb + 3] * inv) << 16);
          uint2 st; st.x = lo; st.y = hi2;
          *(uint2*)(orow + 32 + 8 * rq + 4 * hi) = st;
        }
      }
    }
    __syncthreads();  // protect comb before phase-1 overwrite
  }
}

extern "C" void kernel_launch(void* const* d_in, const int* in_sizes, int n_in,
                              void* d_out, int out_size, void* d_ws, size_t ws_size,
                              hipStream_t stream) {
  const float* x    = (const float*)d_in[0];
  const int*   mask = (const int*)d_in[1];
  const float* Wqkv = (const float*)d_in[2];
  const float* Wout = (const float*)d_in[3];
  const float* bout = (const float*)d_in[4];
  float* out = (float*)d_out;

  char* ws = (char*)d_ws;
  // layout (bytes): [0,8M) xb / attnb; [8M,14M) Wqkv_t, later [8M,10M) Wout_t + [10M,10.5M) maskbits;
  // [14M,22M) Qb; [22M,30M) Kb; [30M,38M) Vt
  u16* xb     = (u16*)(ws);
  u16* attnb  = xb;
  u16* Wqkv_t = (u16*)(ws + (size_t)(8u << 20));
  u16* Wout_t = Wqkv_t;
  u64* mbits  = (u64*)(ws + (size_t)(10u << 20));
  u16* Qb     = (u16*)(ws + (size_t)(14u << 20));
  u16* Kb     = (u16*)(ws + (size_t)(22u << 20));
  u16* Vt     = (u16*)(ws + (size_t)(30u << 20));

  cast_bf16_kernel<<<4096, 256, 0, stream>>>(x, xb, 4096 * 1024 / 4);
  transpose_cast_kernel<<<dim3(96, 32), dim3(32, 8), 0, stream>>>(Wqkv, Wqkv_t, 1024, 3072);
  gemm_qkv_kernel<<<dim3(24, 32), 256, 0, stream>>>(xb, Wqkv_t, Qb, Kb, Vt);
  transpose_cast_kernel<<<dim3(32, 32), dim3(32, 8), 0, stream>>>(Wout, Wout_t, 1024, 1024);
  maskbits_kernel<<<16384, 256, 0, stream>>>(mask, mbits);
  attn_kernel<<<dim3(16, 32), 512, 0, stream>>>(Qb, Kb, Vt, mbits, attnb);
  gemm_out_kernel<<<dim3(8, 32), 256, 0, stream>>>(attnb, Wout_t, bout, out);
}

// Round 7
// 163.242 us; speedup vs baseline: 3.2236x; 1.3387x over previous
//
#include <hip/hip_runtime.h>
#include <hip/hip_bf16.h>

typedef __bf16 bf16x8 __attribute__((ext_vector_type(8)));
typedef float f32x4 __attribute__((ext_vector_type(4)));
typedef float f32x16 __attribute__((ext_vector_type(16)));
typedef unsigned short u16;
typedef unsigned int u32;
typedef unsigned long long u64;
typedef u32 u32x4v __attribute__((ext_vector_type(4)));

#define QSCALE 0.18033688011112042f  /* log2(e)/8 : folds SCALE and exp->exp2 into Q */

__device__ __forceinline__ u16 f2b(float x) {
  __hip_bfloat16 h = __float2bfloat16(x);
  return __builtin_bit_cast(u16, h);
}

__device__ __forceinline__ float exp2_fast(float x) {
#if __has_builtin(__builtin_amdgcn_exp2f)
  return __builtin_amdgcn_exp2f(x);
#else
  float r; asm("v_exp_f32 %0, %1" : "=v"(r) : "v"(x)); return r;
#endif
}

// async global->LDS, 16B per lane; LDS dest = wave-uniform base + lane*16
__device__ __forceinline__ void gload_lds16(const void* g, void* l) {
  __builtin_amdgcn_global_load_lds((const __attribute__((address_space(1))) u32*)g,
                                   (__attribute__((address_space(3))) u32*)l, 16, 0, 0);
}

// ---------------- cast f32 -> bf16 (4 elems/thread) ----------------
__global__ __launch_bounds__(256) void cast_bf16_kernel(const float* __restrict__ src,
                                                        u16* __restrict__ dst, int n4) {
  int i = blockIdx.x * 256 + threadIdx.x;
  if (i >= n4) return;
  float4 v = ((const float4*)src)[i];
  ushort4 o;
  o.x = f2b(v.x); o.y = f2b(v.y); o.z = f2b(v.z); o.w = f2b(v.w);
  ((ushort4*)dst)[i] = o;
}

// ---------------- transpose+cast: src [R][C] f32 -> dst [C][R] bf16 ----------------
__global__ __launch_bounds__(256) void transpose_cast_kernel(const float* __restrict__ src,
                                                             u16* __restrict__ dst,
                                                             int R, int C) {
  __shared__ float t[32][33];
  int c0 = blockIdx.x * 32, r0 = blockIdx.y * 32;
  int tx = threadIdx.x, ty = threadIdx.y;
  for (int k = 0; k < 32; k += 8)
    t[ty + k][tx] = src[(size_t)(r0 + ty + k) * C + c0 + tx];
  __syncthreads();
  for (int k = 0; k < 32; k += 8)
    dst[(size_t)(c0 + ty + k) * R + r0 + tx] = f2b(t[tx][ty + k]);
}

// ---------------- mask [2048][2048] int32 -> bit-packed u64 words ----------------
__global__ __launch_bounds__(256) void maskbits_kernel(const int* __restrict__ mask,
                                                       u64* __restrict__ bits) {
  int gtid = blockIdx.x * 256 + threadIdx.x;
  int wid = gtid >> 6, lane = gtid & 63;
  int v = mask[(size_t)wid * 64 + lane];
  u64 b = __ballot(v != 0);
  if (lane == 0) bits[wid] = b;
}

// ---------------- QKV GEMM: xb[4096][1024] @ Wqkv_t[3072][1024]^T ----------------
// m97 structure: global_load_lds(16B) staging, 2 barriers per K-step.
// Epilogue scatters into Qb (pre-scaled by QSCALE) / Kb [B][H][N][64], Vt [B][H][64][N].
__global__ __launch_bounds__(256) void gemm_qkv_kernel(const u16* __restrict__ A,
                                                       const u16* __restrict__ Bt,
                                                       u16* __restrict__ Qb,
                                                       u16* __restrict__ Kb,
                                                       u16* __restrict__ Vt) {
  __shared__ u16 lA[128 * 32], lB[128 * 32];
  const int tid = threadIdx.x, lane = tid & 63, w = tid >> 6;
  const int wr = w >> 1, wc = w & 1, lrow = lane & 15, lk = lane >> 4;
  const int bm = blockIdx.y, bn = blockIdx.x;
  const int srow = tid >> 2, scol = (tid & 3) * 8;
  const u16* Arow = A + (size_t)(bm * 128 + srow) * 1024 + scol;
  const u16* Brow = Bt + (size_t)(bn * 128 + srow) * 1024 + scol;
  f32x4 acc[4][4] = {};
  for (int k0 = 0; k0 < 1024; k0 += 32) {
    __syncthreads();  // prior iteration's ds_reads done before overwrite
    gload_lds16(Arow + k0,             (char*)lA + w * 1024);
    gload_lds16(Arow + 64 * 1024 + k0, (char*)lA + 4096 + w * 1024);
    gload_lds16(Brow + k0,             (char*)lB + w * 1024);
    gload_lds16(Brow + 64 * 1024 + k0, (char*)lB + 4096 + w * 1024);
    __syncthreads();  // drains vmcnt: staged data visible
    bf16x8 af[4], bfr[4];
    for (int mi = 0; mi < 4; mi++)
      af[mi] = *(const bf16x8*)&lA[(wr * 64 + mi * 16 + lrow) * 32 + lk * 8];
    for (int ni = 0; ni < 4; ni++)
      bfr[ni] = *(const bf16x8*)&lB[(wc * 64 + ni * 16 + lrow) * 32 + lk * 8];
    for (int mi = 0; mi < 4; mi++)
      for (int ni = 0; ni < 4; ni++)
        acc[mi][ni] = __builtin_amdgcn_mfma_f32_16x16x32_bf16(af[mi], bfr[ni], acc[mi][ni], 0, 0, 0);
  }
  const int rowbase = bm * 128 + wr * 64;
  const int colbase = bn * 128 + wc * 64;
  for (int mi = 0; mi < 4; mi++)
    for (int ni = 0; ni < 4; ni++)
      for (int r = 0; r < 4; r++) {
        int row = rowbase + mi * 16 + lk * 4 + r;
        int col = colbase + ni * 16 + lrow;
        int b = row >> 11, n = row & 2047;
        int which = col >> 10, within = col & 1023;
        int h = within >> 6, d = within & 63;
        float av = acc[mi][ni][r];
        size_t bh = (size_t)(b * 16 + h);
        if (which == 0)      Qb[(bh * 2048 + n) * 64 + d] = f2b(av * QSCALE);
        else if (which == 1) Kb[(bh * 2048 + n) * 64 + d] = f2b(av);
        else                 Vt[(bh * 64 + d) * 2048 + n] = f2b(av);
      }
}

// ---------------- out-proj GEMM: attnb[4096][1024] @ Wout_t[1024][1024]^T + bias ----------------
__global__ __launch_bounds__(256) void gemm_out_kernel(const u16* __restrict__ A,
                                                       const u16* __restrict__ Bt,
                                                       const float* __restrict__ bias,
                                                       float* __restrict__ out) {
  __shared__ u16 lA[128 * 32], lB[128 * 32];
  const int tid = threadIdx.x, lane = tid & 63, w = tid >> 6;
  const int wr = w >> 1, wc = w & 1, lrow = lane & 15, lk = lane >> 4;
  const int bm = blockIdx.y, bn = blockIdx.x;
  const int srow = tid >> 2, scol = (tid & 3) * 8;
  const u16* Arow = A + (size_t)(bm * 128 + srow) * 1024 + scol;
  const u16* Brow = Bt + (size_t)(bn * 128 + srow) * 1024 + scol;
  f32x4 acc[4][4] = {};
  for (int k0 = 0; k0 < 1024; k0 += 32) {
    __syncthreads();
    gload_lds16(Arow + k0,             (char*)lA + w * 1024);
    gload_lds16(Arow + 64 * 1024 + k0, (char*)lA + 4096 + w * 1024);
    gload_lds16(Brow + k0,             (char*)lB + w * 1024);
    gload_lds16(Brow + 64 * 1024 + k0, (char*)lB + 4096 + w * 1024);
    __syncthreads();
    bf16x8 af[4], bfr[4];
    for (int mi = 0; mi < 4; mi++)
      af[mi] = *(const bf16x8*)&lA[(wr * 64 + mi * 16 + lrow) * 32 + lk * 8];
    for (int ni = 0; ni < 4; ni++)
      bfr[ni] = *(const bf16x8*)&lB[(wc * 64 + ni * 16 + lrow) * 32 + lk * 8];
    for (int mi = 0; mi < 4; mi++)
      for (int ni = 0; ni < 4; ni++)
        acc[mi][ni] = __builtin_amdgcn_mfma_f32_16x16x32_bf16(af[mi], bfr[ni], acc[mi][ni], 0, 0, 0);
  }
  const int rowbase = bm * 128 + wr * 64;
  const int colbase = bn * 128 + wc * 64;
  for (int mi = 0; mi < 4; mi++)
    for (int ni = 0; ni < 4; ni++)
      for (int r = 0; r < 4; r++) {
        int row = rowbase + mi * 16 + lk * 4 + r;
        int col = colbase + ni * 16 + lrow;
        out[(size_t)row * 1024 + col] = acc[mi][ni][r] + bias[col];
      }
}

// ---------------- flash attention: swapped QK^T (32x32), block-cooperative LDS K/V ----
// grid (16, 32), block 256 = 4 waves; wave w owns q rows [qt*128+w*32, +32); kv chunks 64.
// Per chunk: block stages K[64][64] and V^T[64][64] into LDS (global_load_lds, XOR-swizzled
// via pre-swizzled global source, rule #21), double-buffered, ONE barrier per chunk.
// S^T = mfma(K, Q); per-lane softmax (raw-max, deferred rescale THR=8, log2 domain);
// P repacked through per-wave LDS; O^T = mfma(V^T, P^T).
__global__ __launch_bounds__(256, 3) void attn_kernel(const u16* __restrict__ Qb,
                                                      const u16* __restrict__ Kb,
                                                      const u16* __restrict__ Vt,
                                                      const u64* __restrict__ Mb,
                                                      u16* __restrict__ attnb) {
  __shared__ u16 Klds[2][64 * 64];  // [buf][kv][d], 128B rows, 16B-unit XOR swizzle u^=(row&7)
  __shared__ u16 Vlds[2][64 * 64];  // [buf][d][kv], same swizzle
  __shared__ u32 Plds[4][32 * 32];  // per-wave [kvpair=32][q=32]
  const int tid = threadIdx.x, lane = tid & 63, w = tid >> 6;
  const int l31 = lane & 31, hi = lane >> 5;
  const int qt = blockIdx.x, bh = blockIdx.y;
  const int h = bh & 15, b = bh >> 4;
  const int q = qt * 128 + w * 32 + l31;
  const u16* Qp = Qb + (size_t)bh * 2048 * 64;
  const u16* Kp = Kb + (size_t)bh * 2048 * 64;
  const u16* Vp = Vt + (size_t)bh * 64 * 2048;
  const u64* Mrow = Mb + (size_t)q * 32;
  u32* myP = &Plds[w][0];

  // staging: wave w covers rows [16w,16w+16) of both K and V^T tiles (4 instrs)
  const int rsub = lane >> 3;                       // 0..7
  const int usrc = ((lane & 7) ^ rsub) * 8;         // pre-swizzled source 16B unit
  auto stage = [&](int bi, int j0) {
#pragma unroll
    for (int j = 0; j < 2; j++) {
      const int i = w * 2 + j;                      // instr index 0..7
      const int row = 8 * i + rsub;
      gload_lds16(Kp + (size_t)(j0 + row) * 64 + usrc, (char*)&Klds[bi][0] + i * 1024);
      gload_lds16(Vp + (size_t)row * 2048 + j0 + usrc, (char*)&Vlds[bi][0] + i * 1024);
    }
  };

  // Q B-frags: col=q=lane&31, k-half by hi; resident whole kernel
  bf16x8 qf[4];
#pragma unroll
  for (int t = 0; t < 4; t++)
    qf[t] = *(const bf16x8*)&Qp[(size_t)q * 64 + t * 16 + hi * 8];

  f32x16 acc0 = {}, acc1 = {};  // O^T: d in [0,32) / [32,64), col=q
  float m_run = -3.0e38f, lsum = 0.f;

  stage(0, 0);
  u64 mw = Mrow[0];
  int cur = 0;

  for (int c = 0; c < 32; c++) {
    __syncthreads();  // drains vmcnt: buf[cur] staged; prior reads of buf[cur^1] done
    if (c + 1 < 32) stage(cur ^ 1, (c + 1) * 64);
    u64 mw_n = (c + 1 < 32) ? Mrow[c + 1] : 0;

    // K frags from LDS (swizzled read)
    bf16x8 kc[2][4];
#pragma unroll
    for (int t2 = 0; t2 < 2; t2++)
#pragma unroll
      for (int t = 0; t < 4; t++) {
        const int row = t2 * 32 + l31;
        const int u = (t * 2 + hi) ^ (l31 & 7);
        kc[t2][t] = *(const bf16x8*)((const char*)&Klds[cur][0] + row * 128 + u * 16);
      }

    // S^T = K·Q^T over d=64 (log2-scaled already)
    f32x16 s0 = {}, s1 = {};
    __builtin_amdgcn_s_setprio(1);
#pragma unroll
    for (int t = 0; t < 4; t++) {
      s0 = __builtin_amdgcn_mfma_f32_32x32x16_bf16(kc[0][t], qf[t], s0, 0, 0, 0);
      s1 = __builtin_amdgcn_mfma_f32_32x32x16_bf16(kc[1][t], qf[t], s1, 0, 0, 0);
    }
    __builtin_amdgcn_s_setprio(0);

    // V frags from LDS, issued now so latency hides under softmax
    bf16x8 va[2][4];
#pragma unroll
    for (int dt = 0; dt < 2; dt++)
#pragma unroll
      for (int kk = 0; kk < 4; kk++) {
        const int row = dt * 32 + l31;
        const int u = (kk * 2 + hi) ^ (l31 & 7);
        va[dt][kk] = *(const bf16x8*)((const char*)&Vlds[cur][0] + row * 128 + u * 16);
      }

    // raw row-max (mask applied later by zeroing p; same softmax), tree + partner
    float mx[8];
#pragma unroll
    for (int i = 0; i < 8; i++)
      mx[i] = fmaxf(fmaxf(s0[i], s0[i + 8]), fmaxf(s1[i], s1[i + 8]));
    float m01 = fmaxf(mx[0], mx[1]), m23 = fmaxf(mx[2], mx[3]);
    float m45 = fmaxf(mx[4], mx[5]), m67 = fmaxf(mx[6], mx[7]);
    float pm = fmaxf(fmaxf(m01, m23), fmaxf(m45, m67));
    pm = fmaxf(pm, __shfl_xor(pm, 32, 64));

    // deferred rescale (THR=8 in log2 domain -> p bounded by 256)
    if (__any(pm > m_run + 8.f)) {
      float mn = fmaxf(m_run, pm);
      float fs = exp2_fast(m_run - mn);
      m_run = mn;
      lsum *= fs;
      acc0 *= fs;
      acc1 *= fs;
    }

    // p = exp2(s - m), mask-zero, partial sums, pack kv-pairs -> LDS [kv/2][q]
    u32 w0s = (u32)(mw >> (4 * hi));          // tile0 bits, pre-shifted by 4*hi
    u32 w1s = (u32)((mw >> 32) >> (4 * hi));  // tile1 bits
#pragma unroll
    for (int p = 0; p < 8; p++) {
      const int r0 = 2 * p;
      const int sh = (r0 & 3) + 8 * (p >> 1);           // kv_local - 4*hi for reg r0
      const int wrow = (p & 1) + 4 * (p >> 1) + 2 * hi; // kv pair row (tile0)
      float a0 = exp2_fast(s0[r0] - m_run);
      float a1 = exp2_fast(s0[r0 + 1] - m_run);
      float b0 = exp2_fast(s1[r0] - m_run);
      float b1 = exp2_fast(s1[r0 + 1] - m_run);
      a0 = ((w0s >> sh) & 1u) ? a0 : 0.f;
      a1 = ((w0s >> (sh + 1)) & 1u) ? a1 : 0.f;
      b0 = ((w1s >> sh) & 1u) ? b0 : 0.f;
      b1 = ((w1s >> (sh + 1)) & 1u) ? b1 : 0.f;
      lsum += (a0 + a1) + (b0 + b1);
      myP[wrow * 32 + l31]        = (u32)f2b(a0) | ((u32)f2b(a1) << 16);
      myP[(wrow + 16) * 32 + l31] = (u32)f2b(b0) | ((u32)f2b(b1) << 16);
    }

    // PV: B-frags read back from LDS (contiguous kv per lane), A = V^T
    asm volatile("s_waitcnt lgkmcnt(0)" ::: "memory");
    __builtin_amdgcn_s_setprio(1);
#pragma unroll
    for (int kk = 0; kk < 4; kk++) {
      const int base = (kk * 8 + hi * 4) * 32 + l31;
      u32 r0 = myP[base];
      u32 r1 = myP[base + 32];
      u32 r2 = myP[base + 64];
      u32 r3 = myP[base + 96];
      u32x4v pv4 = {r0, r1, r2, r3};
      bf16x8 pbf = __builtin_bit_cast(bf16x8, pv4);
      acc0 = __builtin_amdgcn_mfma_f32_32x32x16_bf16(va[0][kk], pbf, acc0, 0, 0, 0);
      acc1 = __builtin_amdgcn_mfma_f32_32x32x16_bf16(va[1][kk], pbf, acc1, 0, 0, 0);
    }
    __builtin_amdgcn_s_setprio(0);

    mw = mw_n;
    cur ^= 1;
  }

  // finalize: partner-sum, divide, store O^T rows (d) for this q
  lsum += __shfl_xor(lsum, 32, 64);
  float inv = 1.0f / lsum;
  u16* orow = attnb + ((size_t)b * 2048 + q) * 1024 + h * 64;
#pragma unroll
  for (int rq = 0; rq < 4; rq++) {
    const int rb = rq * 4;
    {
      u32 lo = (u32)f2b(acc0[rb] * inv) | ((u32)f2b(acc0[rb + 1] * inv) << 16);
      u32 hi2 = (u32)f2b(acc0[rb + 2] * inv) | ((u32)f2b(acc0[rb + 3] * inv) << 16);
      uint2 st; st.x = lo; st.y = hi2;
      *(uint2*)(orow + 8 * rq + 4 * hi) = st;
    }
    {
      u32 lo = (u32)f2b(acc1[rb] * inv) | ((u32)f2b(acc1[rb + 1] * inv) << 16);
      u32 hi2 = (u32)f2b(acc1[rb + 2] * inv) | ((u32)f2b(acc1[rb + 3] * inv) << 16);
      uint2 st; st.x = lo; st.y = hi2;
      *(uint2*)(orow + 32 + 8 * rq + 4 * hi) = st;
    }
  }
}

extern "C" void kernel_launch(void* const* d_in, const int* in_sizes, int n_in,
                              void* d_out, int out_size, void* d_ws, size_t ws_size,
                              hipStream_t stream) {
  const float* x    = (const float*)d_in[0];
  const int*   mask = (const int*)d_in[1];
  const float* Wqkv = (const float*)d_in[2];
  const float* Wout = (const float*)d_in[3];
  const float* bout = (const float*)d_in[4];
  float* out = (float*)d_out;

  char* ws = (char*)d_ws;
  // layout (bytes): [0,8M) xb / attnb; [8M,14M) Wqkv_t, later [8M,10M) Wout_t + [10M,10.5M) maskbits;
  // [14M,22M) Qb; [22M,30M) Kb; [30M,38M) Vt
  u16* xb     = (u16*)(ws);
  u16* attnb  = xb;
  u16* Wqkv_t = (u16*)(ws + (size_t)(8u << 20));
  u16* Wout_t = Wqkv_t;
  u64* mbits  = (u64*)(ws + (size_t)(10u << 20));
  u16* Qb     = (u16*)(ws + (size_t)(14u << 20));
  u16* Kb     = (u16*)(ws + (size_t)(22u << 20));
  u16* Vt     = (u16*)(ws + (size_t)(30u << 20));

  cast_bf16_kernel<<<4096, 256, 0, stream>>>(x, xb, 4096 * 1024 / 4);
  transpose_cast_kernel<<<dim3(96, 32), dim3(32, 8), 0, stream>>>(Wqkv, Wqkv_t, 1024, 3072);
  gemm_qkv_kernel<<<dim3(24, 32), 256, 0, stream>>>(xb, Wqkv_t, Qb, Kb, Vt);
  transpose_cast_kernel<<<dim3(32, 32), dim3(32, 8), 0, stream>>>(Wout, Wout_t, 1024, 1024);
  maskbits_kernel<<<16384, 256, 0, stream>>>(mask, mbits);
  attn_kernel<<<dim3(16, 32), 256, 0, stream>>>(Qb, Kb, Vt, mbits, attnb);
  gemm_out_kernel<<<dim3(8, 32), 256, 0, stream>>>(attnb, Wout_t, bout, out);
}